// Round 5
// baseline (550.802 us; speedup 1.0000x reference)
//
#include <hip/hip_runtime.h>
#include <stdint.h>

typedef __attribute__((ext_vector_type(8))) short short8;   // 8 bf16 (4 VGPRs)
typedef __attribute__((ext_vector_type(4))) float float4v;  // 16B loads
typedef __attribute__((ext_vector_type(16))) float f32x16;  // 32x32 MFMA C/D

#define B_  16
#define S_  4096
#define D_  128
#define TM  64          // Q rows per block (2 q-groups x 32)
#define TN  64          // keys per tile (2 key-groups x 32)
#define NT_ (S_ / TN)   // 64 key-tiles per batch
#define IMG 8192        // shorts per 64x128 tile image (16 KB)

#define ZERO16 {0.f,0.f,0.f,0.f, 0.f,0.f,0.f,0.f, 0.f,0.f,0.f,0.f, 0.f,0.f,0.f,0.f}

// fp32 -> bf16 round-to-nearest-even
__device__ __forceinline__ unsigned short f2bf(float f) {
    union { float f; uint32_t u; } c; c.f = f;
    uint32_t u = c.u + 0x7FFFu + ((c.u >> 16) & 1u);
    return (unsigned short)(u >> 16);
}

__device__ __forceinline__ uint4 pack8(float4v x, float4v y) {
    uint4 r;
    r.x = (uint32_t)f2bf(x[0]) | ((uint32_t)f2bf(x[1]) << 16);
    r.y = (uint32_t)f2bf(x[2]) | ((uint32_t)f2bf(x[3]) << 16);
    r.z = (uint32_t)f2bf(y[0]) | ((uint32_t)f2bf(y[1]) << 16);
    r.w = (uint32_t)f2bf(y[2]) | ((uint32_t)f2bf(y[3]) << 16);
    return r;
}

// async global->LDS, 16 B per lane; lds dest = wave-uniform base + lane*16
__device__ __forceinline__ void gload16(const unsigned short* g, unsigned short* l) {
    __builtin_amdgcn_global_load_lds(
        (const __attribute__((address_space(1))) unsigned int*)g,
        (__attribute__((address_space(3))) unsigned int*)l, 16, 0, 0);
}

// packed fp32x2 -> bf16x2 (RTNE); no builtin on gfx950 -> inline asm
__device__ __forceinline__ uint32_t cvtpk(float lo, float hi) {
    uint32_t w;
    asm("v_cvt_pk_bf16_f32 %0, %1, %2" : "=v"(w) : "v"(lo), "v"(hi));
    return w;
}

// Build PV A-fragment from 8 in-register P values (chunk of 16 keys).
// Lane (q=l&31, hi=l>>5) holds chunk-keys {0,1,2,3,8,9,10,11}+4*hi.
// v_permlane32_swap_b32 vdst,vsrc swaps vdst's HI-lanes with vsrc's LO-lanes:
//   swap(xa, ya): xa' = [own {0,1} | partner {8,9}]   = word0
//                 ya' = [partner {4,5} | own {12,13}]  = word2
__device__ __forceinline__ short8 build_pfrag(const float* p) {
    uint32_t xa = cvtpk(p[0], p[1]);
    uint32_t xb = cvtpk(p[2], p[3]);
    uint32_t ya = cvtpk(p[4], p[5]);
    uint32_t yb = cvtpk(p[6], p[7]);
    asm("v_permlane32_swap_b32 %0, %1" : "+v"(xa), "+v"(ya));
    asm("v_permlane32_swap_b32 %0, %1" : "+v"(xb), "+v"(yb));
    union { uint32_t u[4]; short8 s; } r;
    r.u[0] = xa; r.u[1] = xb; r.u[2] = ya; r.u[3] = yb;
    return r.s;
}

// ---------------- pre-pass: bf16 tile images with baked-in XOR swizzle -------
// K image: img[row][cb'][8] = K[row][ (cb'^(row&15))*8 .. +8 ]   (row 0..63, cb' 0..15)
// V image: img[dr][cb'][j]  = V[ (cb'^(dr&7))*8 + j ][dr]        (dr 0..127, cb' 0..7)
__global__ __launch_bounds__(256)
void prepass(const float* __restrict__ Kg, const float* __restrict__ Vg,
             unsigned short* __restrict__ Kb, unsigned short* __restrict__ Vb)
{
    const int t = threadIdx.x;
    const int tile = blockIdx.x, b = blockIdx.y;
    const size_t img = (size_t)(b * NT_ + tile) * IMG;

    const float* ksrc = Kg + ((size_t)b * S_ + tile * TN) * D_;
    const float* vsrc = Vg + ((size_t)b * S_ + tile * TN) * D_;
    unsigned short* kdst = Kb + img;
    unsigned short* vdst = Vb + img;

    // ---- issue ALL loads first (16 x 16B per thread in flight) ----
    float4v kx[4], ky[4];
    #pragma unroll
    for (int i = 0; i < 4; ++i) {
        int bid = i * 256 + t;           // 16B-block id 0..1023
        int row = bid >> 4, cbp = bid & 15;
        int cb  = cbp ^ (row & 15);      // 16-slot swizzle
        const float* s = ksrc + row * D_ + cb * 8;
        kx[i] = *(const float4v*)s;
        ky[i] = *(const float4v*)(s + 4);
    }
    const int kb = t >> 5, cg = t & 31;
    float4v v[8];
    #pragma unroll
    for (int r = 0; r < 8; ++r)
        v[r] = *(const float4v*)(vsrc + (kb * 8 + r) * D_ + cg * 4);

    // ---- K image stores (linear, coalesced) ----
    #pragma unroll
    for (int i = 0; i < 4; ++i) {
        int bid = i * 256 + t;
        *(uint4*)(kdst + (size_t)bid * 8) = pack8(kx[i], ky[i]);
    }

    // ---- V register transpose + direct swizzled-image stores ----
    #pragma unroll
    for (int j = 0; j < 4; ++j) {
        int dr = cg * 4 + j;
        uint4 w;
        w.x = (uint32_t)f2bf(v[0][j]) | ((uint32_t)f2bf(v[1][j]) << 16);
        w.y = (uint32_t)f2bf(v[2][j]) | ((uint32_t)f2bf(v[3][j]) << 16);
        w.z = (uint32_t)f2bf(v[4][j]) | ((uint32_t)f2bf(v[5][j]) << 16);
        w.w = (uint32_t)f2bf(v[6][j]) | ((uint32_t)f2bf(v[7][j]) << 16);
        *(uint4*)(vdst + dr * 64 + (kb ^ (dr & 7)) * 8) = w;
    }
}

// ---------------- main flash-attention kernel --------------------------------
// 4 waves = 2 q-groups x 2 key-groups; 32x32x16 MFMA; in-register softmax.
// Pipelined single-buffer staging: K consumed early (QK), V late (PV), so
// stageK(t+1) is issued right after QK(t) frees Ks and stageV(t+1) right
// after PV(t) frees Vt. Counted vmcnt(4) waits keep 4-8 DMA loads in flight
// across raw s_barriers -- vmcnt never drains to 0 in the loop (T3/T4).
__global__ __launch_bounds__(256, 4)
void attn_fwd(const float* __restrict__ Qg,
              const unsigned short* __restrict__ Kb,
              const unsigned short* __restrict__ Vb,
              const int* __restrict__ VL,
              float* __restrict__ Og)
{
    __shared__ __align__(16) unsigned short SM[2 * IMG];   // Ks | Vt, 32 KB
    __shared__ float Ls[128];
    unsigned short* Ks = SM;
    unsigned short* Vt = SM + IMG;

    const int t    = threadIdx.x;
    const int wave = t >> 6;        // 0..3
    const int lane = t & 63;
    const int l31  = lane & 31;     // q column within wave tile
    const int hi   = lane >> 5;     // half-wave
    const int wq   = wave >> 1;     // q group (0..1)
    const int wk   = wave & 1;      // key group (0..1)

    const int b  = blockIdx.y;
    const int q0 = blockIdx.x * TM;
    const int nvalid = VL[b];
    const int ntiles = (nvalid + TN - 1) / TN;

    const unsigned short* kbase = Kb + (size_t)b * NT_ * IMG;
    const unsigned short* vbase = Vb + (size_t)b * NT_ * IMG;

    // 1/sqrt(128) * log2(e) : p = exp2(s') == exp(s/sqrt(d))
    const float qscale = 0.08838834764831845f * 1.4426950408889634f;

    // Q fragments (B operand of swapped QK): lane holds Q[q=l31][d=ks*16+hi*8+j]
    short8 qf[8];
    {
        const float* qp = Qg + ((size_t)b * S_ + (q0 + wq * 32 + l31)) * D_;
        #pragma unroll
        for (int ks = 0; ks < 8; ++ks) {
            float4v x = *(const float4v*)(qp + ks * 16 + hi * 8);
            float4v y = *(const float4v*)(qp + ks * 16 + hi * 8 + 4);
            #pragma unroll
            for (int j = 0; j < 4; ++j) { x[j] *= qscale; y[j] *= qscale; }
            union { uint4 u; short8 s; } cv; cv.u = pack8(x, y);
            qf[ks] = cv.s;
        }
    }

    f32x16 zz = ZERO16;
    f32x16 oacc[4];
    oacc[0] = zz; oacc[1] = zz; oacc[2] = zz; oacc[3] = zz;
    float lsum = 0.f;

    const int swk = l31 & 15;   // K image swizzle key ((wk*32+l31)&15 == l31&15)
    const int swv = l31 & 7;    // V image swizzle key (dr&7)

    // ---- prologue: stage tile 0 (4 K loads then 4 V loads per thread) ----
    {
        const unsigned short* kimg = kbase;
        #pragma unroll
        for (int i = 0; i < 4; ++i)
            gload16(kimg + (i * 256 + t) * 8, &Ks[(i * 256 + wave * 64) * 8]);
        const unsigned short* vimg = vbase;
        #pragma unroll
        for (int i = 0; i < 4; ++i)
            gload16(vimg + (i * 256 + t) * 8, &Vt[(i * 256 + wave * 64) * 8]);
    }

    for (int tile = 0; tile < ntiles; ++tile) {
        const int n0 = tile * TN;
        // next tile to prefetch; re-stage current on last iter (keeps vmcnt
        // counts uniform, no OOB, no branches around the issue)
        const int nx = (tile + 1 < ntiles) ? tile + 1 : tile;

        // A: my 4 K loads landed (4 V loads may still fly); all waves ready
        asm volatile("s_waitcnt vmcnt(4)" ::: "memory");
        __builtin_amdgcn_sched_barrier(0);
        __builtin_amdgcn_s_barrier();

        // B: S^T = K Q^T : one 32(key) x 32(q) tile per wave
        f32x16 st = zz;
        {
            const unsigned short* k0 = &Ks[(wk * 32 + l31) * D_];
            __builtin_amdgcn_s_setprio(1);
            #pragma unroll
            for (int ks = 0; ks < 8; ++ks) {
                int sl = (((ks << 1) | hi) ^ swk) << 3;
                short8 a0 = *(const short8*)(k0 + sl);
                st = __builtin_amdgcn_mfma_f32_32x32x16_bf16(a0, qf[ks], st, 0, 0, 0);
            }
            __builtin_amdgcn_s_setprio(0);
        }

        // C: Ks reads retired across all waves -> Ks is free
        asm volatile("s_waitcnt lgkmcnt(0)" ::: "memory");
        __builtin_amdgcn_sched_barrier(0);
        __builtin_amdgcn_s_barrier();

        // D: prefetch K(nx) into Ks (lands before A of next iter's vmcnt(4))
        {
            const unsigned short* kimg = kbase + (size_t)nx * IMG;
            #pragma unroll
            for (int i = 0; i < 4; ++i)
                gload16(kimg + (i * 256 + t) * 8, &Ks[(i * 256 + wave * 64) * 8]);
        }

        // E: softmax in registers (covers V(t) flight)
        // lane holds S^T[key = n0 + wk*32 + (r&3)+8*(r>>2)+4*hi][q = l31]
        float p[16];
        const bool full = (n0 + TN) <= nvalid;
        if (full) {
            #pragma unroll
            for (int r = 0; r < 16; ++r) { p[r] = exp2f(st[r]); lsum += p[r]; }
        } else {
            #pragma unroll
            for (int r = 0; r < 16; ++r) {
                int key = n0 + wk * 32 + (r & 3) + 8 * (r >> 2) + 4 * hi;
                float e = exp2f(st[r]);
                p[r] = (key < nvalid) ? e : 0.f; lsum += p[r];
            }
        }
        short8 pf0 = build_pfrag(p);       // keys n0 + wk*32 +  0..15
        short8 pf1 = build_pfrag(p + 8);   // keys n0 + wk*32 + 16..31

        // F: my V(t) landed (4 K(nx) loads still fly); all waves' V landed
        asm volatile("s_waitcnt vmcnt(4)" ::: "memory");
        __builtin_amdgcn_sched_barrier(0);
        __builtin_amdgcn_s_barrier();

        // G: O += P V (this wave's 32-key slice)
        __builtin_amdgcn_s_setprio(1);
        #pragma unroll
        for (int dt = 0; dt < 4; ++dt) {
            const unsigned short* vrow = &Vt[(dt * 32 + l31) * TN];
            int s0 = ((((wk * 2 + 0) << 1) | hi) ^ swv) << 3;
            int s1 = ((((wk * 2 + 1) << 1) | hi) ^ swv) << 3;
            short8 v0 = *(const short8*)(vrow + s0);
            short8 v1 = *(const short8*)(vrow + s1);
            oacc[dt] = __builtin_amdgcn_mfma_f32_32x32x16_bf16(pf0, v0, oacc[dt], 0, 0, 0);
            oacc[dt] = __builtin_amdgcn_mfma_f32_32x32x16_bf16(pf1, v1, oacc[dt], 0, 0, 0);
        }
        __builtin_amdgcn_s_setprio(0);

        // H: Vt reads retired across all waves -> Vt is free
        asm volatile("s_waitcnt lgkmcnt(0)" ::: "memory");
        __builtin_amdgcn_sched_barrier(0);
        __builtin_amdgcn_s_barrier();

        // I: prefetch V(nx) into Vt (lands before F of next iter's vmcnt(4))
        {
            const unsigned short* vimg = vbase + (size_t)nx * IMG;
            #pragma unroll
            for (int i = 0; i < 4; ++i)
                gload16(vimg + (i * 256 + t) * 8, &Vt[(i * 256 + wave * 64) * 8]);
        }
    }

    // ---- drain outstanding DMA before reusing SM for the reduction ----
    asm volatile("s_waitcnt vmcnt(0)" ::: "memory");
    __builtin_amdgcn_sched_barrier(0);

    // ---- cross-wave-pair reduction (wk=1 -> wk=0) through LDS, once/block ----
    float lpart = lsum + __shfl_xor(lsum, 32);

    float* red = (float*)SM;   // 64 idx x 128 lanes = 32 KB, conflict-free layout
    __syncthreads();           // all DMA landed + all tile-loop activity done
    if (wk == 1) {
        #pragma unroll
        for (int dt = 0; dt < 4; ++dt)
            #pragma unroll
            for (int r = 0; r < 16; ++r)
                red[(dt * 16 + r) * 128 + wq * 64 + lane] = oacc[dt][r];
        Ls[wq * 64 + lane] = lpart;
    }
    __syncthreads();
    if (wk == 0) {
        #pragma unroll
        for (int dt = 0; dt < 4; ++dt)
            #pragma unroll
            for (int r = 0; r < 16; ++r)
                oacc[dt][r] += red[(dt * 16 + r) * 128 + wq * 64 + lane];

        float ltot = lpart + Ls[wq * 64 + lane];
        float inv  = 1.0f / ltot;   // for q = l31

        float* op = Og + ((size_t)b * S_ + (q0 + wq * 32)) * D_ + l31;
        #pragma unroll
        for (int r = 0; r < 16; ++r) {
            const int qc = (r & 3) + 8 * (r >> 2);     // + 4*hi at runtime
            float invr = __shfl(inv, qc + 4 * hi, 32); // inv of this reg's q-row
            #pragma unroll
            for (int dt = 0; dt < 4; ++dt)
                op[(qc + 4 * hi) * D_ + dt * 32] = oacc[dt][r] * invr;
        }
    }
}

extern "C" void kernel_launch(void* const* d_in, const int* in_sizes, int n_in,
                              void* d_out, int out_size, void* d_ws, size_t ws_size,
                              hipStream_t stream) {
    const float* Q = (const float*)d_in[0];
    const float* K = (const float*)d_in[1];
    const float* V = (const float*)d_in[2];
    const int*   L = (const int*)d_in[3];
    float*       O = (float*)d_out;

    unsigned short* Kb = (unsigned short*)d_ws;                   // 16.8 MB
    unsigned short* Vb = Kb + (size_t)B_ * S_ * D_;               // 16.8 MB

    dim3 grid(NT_, B_);
    prepass<<<grid, 256, 0, stream>>>(K, V, Kb, Vb);
    dim3 grid2(S_ / TM, B_);
    attn_fwd<<<grid2, 256, 0, stream>>>(Q, Kb, Vb, L, O);
}

// Round 6
// 238.488 us; speedup vs baseline: 2.3096x; 2.3096x over previous
//
#include <hip/hip_runtime.h>
#include <stdint.h>

typedef __attribute__((ext_vector_type(8))) short short8;   // 8 bf16 (4 VGPRs)
typedef __attribute__((ext_vector_type(4))) float float4v;  // MFMA C/D + 16B loads

#define B_  16
#define S_  4096
#define D_  128
#define TM  64          // Q rows per block (4 waves x 16)
#define TN  64          // keys per tile
#define NT_ (S_ / TN)   // 64 key-tiles per batch
#define IMG 8192        // shorts per 64x128 tile image (16 KB)

// fp32 -> bf16 round-to-nearest-even
__device__ __forceinline__ unsigned short f2bf(float f) {
    union { float f; uint32_t u; } c; c.f = f;
    uint32_t u = c.u + 0x7FFFu + ((c.u >> 16) & 1u);
    return (unsigned short)(u >> 16);
}

__device__ __forceinline__ uint4 pack8(float4v x, float4v y) {
    uint4 r;
    r.x = (uint32_t)f2bf(x[0]) | ((uint32_t)f2bf(x[1]) << 16);
    r.y = (uint32_t)f2bf(x[2]) | ((uint32_t)f2bf(x[3]) << 16);
    r.z = (uint32_t)f2bf(y[0]) | ((uint32_t)f2bf(y[1]) << 16);
    r.w = (uint32_t)f2bf(y[2]) | ((uint32_t)f2bf(y[3]) << 16);
    return r;
}

// async global->LDS, 16 B per lane; lds dest = wave-uniform base + lane*16
__device__ __forceinline__ void gload16(const unsigned short* g, unsigned short* l) {
    __builtin_amdgcn_global_load_lds(
        (const __attribute__((address_space(1))) unsigned int*)g,
        (__attribute__((address_space(3))) unsigned int*)l, 16, 0, 0);
}

// ---------------- pre-pass: bf16 tile images with baked-in XOR swizzle -------
// K image: img[row][cb'][8] = K[row][ (cb'^(row&15))*8 .. +8 ]   (row 0..63, cb' 0..15)
// V image: img[dr][cb'][j]  = V[ (cb'^(dr&7))*8 + j ][dr]        (dr 0..127, cb' 0..7)
__global__ __launch_bounds__(256)
void prepass(const float* __restrict__ Kg, const float* __restrict__ Vg,
             unsigned short* __restrict__ Kb, unsigned short* __restrict__ Vb)
{
    const int t = threadIdx.x;
    const int tile = blockIdx.x, b = blockIdx.y;
    const size_t img = (size_t)(b * NT_ + tile) * IMG;

    const float* ksrc = Kg + ((size_t)b * S_ + tile * TN) * D_;
    const float* vsrc = Vg + ((size_t)b * S_ + tile * TN) * D_;
    unsigned short* kdst = Kb + img;
    unsigned short* vdst = Vb + img;

    // ---- issue ALL loads first (16 x 16B per thread in flight) ----
    float4v kx[4], ky[4];
    #pragma unroll
    for (int i = 0; i < 4; ++i) {
        int bid = i * 256 + t;           // 16B-block id 0..1023
        int row = bid >> 4, cbp = bid & 15;
        int cb  = cbp ^ (row & 15);      // 16-slot swizzle
        const float* s = ksrc + row * D_ + cb * 8;
        kx[i] = *(const float4v*)s;
        ky[i] = *(const float4v*)(s + 4);
    }
    const int kb = t >> 5, cg = t & 31;
    float4v v[8];
    #pragma unroll
    for (int r = 0; r < 8; ++r)
        v[r] = *(const float4v*)(vsrc + (kb * 8 + r) * D_ + cg * 4);

    // ---- K image stores (linear, coalesced) ----
    #pragma unroll
    for (int i = 0; i < 4; ++i) {
        int bid = i * 256 + t;
        *(uint4*)(kdst + (size_t)bid * 8) = pack8(kx[i], ky[i]);
    }

    // ---- V register transpose + direct swizzled-image stores ----
    #pragma unroll
    for (int j = 0; j < 4; ++j) {
        int dr = cg * 4 + j;
        uint4 w;
        w.x = (uint32_t)f2bf(v[0][j]) | ((uint32_t)f2bf(v[1][j]) << 16);
        w.y = (uint32_t)f2bf(v[2][j]) | ((uint32_t)f2bf(v[3][j]) << 16);
        w.z = (uint32_t)f2bf(v[4][j]) | ((uint32_t)f2bf(v[5][j]) << 16);
        w.w = (uint32_t)f2bf(v[6][j]) | ((uint32_t)f2bf(v[7][j]) << 16);
        *(uint4*)(vdst + dr * 64 + (kb ^ (dr & 7)) * 8) = w;
    }
}

// ---------------- main flash-attention kernel --------------------------------
// Round-0 body (4 waves x 16 q-rows, 16x16x32 MFMA, P via per-wave LDS) with
// pipelined single-buffer staging: K is consumed early (QK), V late (PV), so
// stage-K(t+1) issues right after QK(t) frees Ks and stage-V(t+1) right after
// PV(t) frees Vt. Counted vmcnt(4) + raw s_barriers; vmcnt never drains to 0
// inside the loop. No sched_barrier(0) (round-5 spill trigger).
__global__ __launch_bounds__(256, 4)
void attn_fwd(const float* __restrict__ Qg,
              const unsigned short* __restrict__ Kb,
              const unsigned short* __restrict__ Vb,
              const int* __restrict__ VL,
              float* __restrict__ Og)
{
    __shared__ __align__(16) unsigned short Ks[TN * D_];     // 16 KB swizzled image
    __shared__ __align__(16) unsigned short Vt[D_ * TN];     // 16 KB swizzled image
    __shared__ __align__(16) unsigned short Ps[4 * 16 * 64]; // 8 KB, per-wave P

    const int t    = threadIdx.x;
    const int wave = t >> 6;
    const int lane = t & 63;
    const int l16  = lane & 15;
    const int quad = lane >> 4;
    const int swv  = l16 & 7;      // V image swizzle key (dr&7)

    const int b  = blockIdx.y;
    const int q0 = blockIdx.x * TM;
    const int nvalid = VL[b];
    const int ntiles = (nvalid + TN - 1) / TN;

    const unsigned short* kbase = Kb + (size_t)b * NT_ * IMG;
    const unsigned short* vbase = Vb + (size_t)b * NT_ * IMG;

    const float scale = 0.08838834764831845f; // 1/sqrt(128), folded into Q

    // Q fragments: A[m=l16][k = ks*32 + quad*8 + j], scaled
    short8 qf[4];
    {
        const float* qp = Qg + ((size_t)b * S_ + (q0 + wave * 16 + l16)) * D_;
        #pragma unroll
        for (int ks = 0; ks < 4; ++ks) {
            float4v x = *(const float4v*)(qp + ks * 32 + quad * 8);
            float4v y = *(const float4v*)(qp + ks * 32 + quad * 8 + 4);
            #pragma unroll
            for (int j = 0; j < 4; ++j) { x[j] *= scale; y[j] *= scale; }
            union { uint4 u; short8 s; } cv; cv.u = pack8(x, y);
            qf[ks] = cv.s;
        }
    }

    float4v oacc[8];
    #pragma unroll
    for (int dt = 0; dt < 8; ++dt) oacc[dt] = (float4v){0.f, 0.f, 0.f, 0.f};
    float lsum[4] = {0.f, 0.f, 0.f, 0.f};

    unsigned short* Pw = Ps + wave * (16 * 64);

    // ---- prologue: stage tile 0 (4 K loads, then 4 V loads, per thread) ----
    #pragma unroll
    for (int i = 0; i < 4; ++i)
        gload16(kbase + (i * 256 + t) * 8, &Ks[(i * 256 + wave * 64) * 8]);
    #pragma unroll
    for (int i = 0; i < 4; ++i)
        gload16(vbase + (i * 256 + t) * 8, &Vt[(i * 256 + wave * 64) * 8]);

    for (int tile = 0; tile < ntiles; ++tile) {
        const int n0 = tile * TN;
        // next tile; re-stage current on last iter (uniform vmcnt, no OOB)
        const int nx = (tile + 1 < ntiles) ? tile + 1 : tile;

        // A: my 4 K loads landed (V may still fly); barrier -> all waves' K landed
        asm volatile("s_waitcnt vmcnt(4)" ::: "memory");
        __builtin_amdgcn_s_barrier();

        // B: S = Q K^T : 16 rows x 64 cols per wave
        float sv[4][4];
        #pragma unroll
        for (int nt = 0; nt < 4; ++nt) {
            float4v sa = (float4v){0.f, 0.f, 0.f, 0.f};
            #pragma unroll
            for (int ks = 0; ks < 4; ++ks) {
                // 16-slot image: slot = ((ks*4+quad) ^ (row&15)), row = nt*16+l16
                short8 bf = *(const short8*)(&Ks[(nt * 16 + l16) * D_ + ((((ks << 2) + quad) ^ l16) << 3)]);
                sa = __builtin_amdgcn_mfma_f32_16x16x32_bf16(qf[ks], bf, sa, 0, 0, 0);
            }
            #pragma unroll
            for (int r = 0; r < 4; ++r) sv[nt][r] = sa[r];
        }

        // C: all my Ks reads retired; barrier -> Ks free block-wide
        asm volatile("s_waitcnt lgkmcnt(0)" ::: "memory");
        __builtin_amdgcn_s_barrier();

        // D: prefetch K(nx) into Ks (lands before next iter's A-wait)
        {
            const unsigned short* kimg = kbase + (size_t)nx * IMG;
            #pragma unroll
            for (int i = 0; i < 4; ++i)
                gload16(kimg + (i * 256 + t) * 8, &Ks[(i * 256 + wave * 64) * 8]);
        }

        // E: p = exp(s), accumulate l, write P (swizzled) -- covers V flight
        const bool full = (n0 + TN) <= nvalid;
        #pragma unroll
        for (int nt = 0; nt < 4; ++nt) {
            const bool ok = full || (n0 + nt * 16 + l16) < nvalid;
            const int cb = nt * 2 + (l16 >> 3);
            #pragma unroll
            for (int r = 0; r < 4; ++r) {
                float p = ok ? __expf(sv[nt][r]) : 0.0f;
                lsum[r] += p;
                const int row = quad * 4 + r;
                Pw[row * 64 + ((cb ^ (row >> 1)) << 3) + swv] = f2bf(p);
            }
        }

        // F: my V loads landed (K(nx) still flies); barrier -> all V landed
        asm volatile("s_waitcnt vmcnt(4)" ::: "memory");
        __builtin_amdgcn_s_barrier();

        // G: O += P V
        #pragma unroll
        for (int ks2 = 0; ks2 < 2; ++ks2) {
            short8 pf = *(const short8*)(&Pw[l16 * 64 + ((((ks2 << 2) + quad) ^ (l16 >> 1)) << 3)]);
            #pragma unroll
            for (int dt = 0; dt < 8; ++dt) {
                short8 vf = *(const short8*)(&Vt[(dt * 16 + l16) * TN + ((((ks2 << 2) + quad) ^ swv) << 3)]);
                oacc[dt] = __builtin_amdgcn_mfma_f32_16x16x32_bf16(pf, vf, oacc[dt], 0, 0, 0);
            }
        }

        // H: all my Vt reads retired; barrier -> Vt free block-wide
        asm volatile("s_waitcnt lgkmcnt(0)" ::: "memory");
        __builtin_amdgcn_s_barrier();

        // I: prefetch V(nx) into Vt (lands before next iter's F-wait)
        {
            const unsigned short* vimg = vbase + (size_t)nx * IMG;
            #pragma unroll
            for (int i = 0; i < 4; ++i)
                gload16(vimg + (i * 256 + t) * 8, &Vt[(i * 256 + wave * 64) * 8]);
        }
    }

    // drain outstanding DMA before kernel end
    asm volatile("s_waitcnt vmcnt(0)" ::: "memory");

    // ---- final: reduce l over the 16-lane group, O /= l, store ----
    float invl[4];
    #pragma unroll
    for (int r = 0; r < 4; ++r) {
        float s = lsum[r];
        #pragma unroll
        for (int off = 1; off < 16; off <<= 1)
            s += __shfl_xor(s, off);
        invl[r] = 1.0f / s;
    }

    float* op = Og + ((size_t)b * S_ + (q0 + wave * 16 + quad * 4)) * D_;
    #pragma unroll
    for (int r = 0; r < 4; ++r) {
        #pragma unroll
        for (int dt = 0; dt < 8; ++dt)
            op[r * D_ + dt * 16 + l16] = oacc[dt][r] * invl[r];
    }
}

extern "C" void kernel_launch(void* const* d_in, const int* in_sizes, int n_in,
                              void* d_out, int out_size, void* d_ws, size_t ws_size,
                              hipStream_t stream) {
    const float* Q = (const float*)d_in[0];
    const float* K = (const float*)d_in[1];
    const float* V = (const float*)d_in[2];
    const int*   L = (const int*)d_in[3];
    float*       O = (float*)d_out;

    unsigned short* Kb = (unsigned short*)d_ws;                   // 16.8 MB
    unsigned short* Vb = Kb + (size_t)B_ * S_ * D_;               // 16.8 MB

    dim3 grid(NT_, B_);
    prepass<<<grid, 256, 0, stream>>>(K, V, Kb, Vb);
    dim3 grid2(S_ / TM, B_);
    attn_fwd<<<grid2, 256, 0, stream>>>(Q, Kb, Vb, L, O);
}